// Round 1
// baseline (88.133 us; speedup 1.0000x reference)
//
#include <hip/hip_runtime.h>
#include <math.h>

// Problem constants
#define NVOX  1048576   // voxels per BC slice (64*128*128)
#define NSLC  4         // dst slice0, dst slice1, ref slice0, ref slice1
#define MFINE 2048      // fine histogram bins over [0,1]
#define BINS  32

// d_ws layout (bytes):
//   [0, 32768)        : uint32 fine[4][2048]   (must be zeroed each call)
//   [32768, 33280)    : float  soft[4][32]
//   [33280, 33536)    : float  gt[2][32]   = g_k * table_k  (per dst slice)
//   [33536, 33664)    : float  gd[32]      = g_k = exp(-k^2/50)

// ---------------------------------------------------------------------------
// K1: fine-grained hard histogram. 256 blocks (64/slice) x 256 threads.
// Each thread: 16 float4 loads = 64 voxels; 1 LDS int atomic per voxel;
// block flushes 2048 global atomics.
// ---------------------------------------------------------------------------
__global__ __launch_bounds__(256) void hist_kernel(const float4* __restrict__ dst4,
                                                   const float4* __restrict__ ref4,
                                                   unsigned int* __restrict__ fine) {
    __shared__ unsigned int h[MFINE];
    const int t  = threadIdx.x;
    const int b  = blockIdx.x;
    const int s  = b >> 6;     // slice 0..3
    const int ib = b & 63;

    for (int i = t; i < MFINE; i += 256) h[i] = 0;
    __syncthreads();

    const float4* src = (s < 2) ? (dst4 + s * (NVOX / 4))
                                : (ref4 + (s - 2) * (NVOX / 4));
    const int base = ib * 4096;   // 4096 float4 per block

    #pragma unroll
    for (int j = 0; j < 16; ++j) {
        float4 v = src[base + j * 256 + t];
        int m0 = min(max((int)(v.x * (float)MFINE), 0), MFINE - 1);
        int m1 = min(max((int)(v.y * (float)MFINE), 0), MFINE - 1);
        int m2 = min(max((int)(v.z * (float)MFINE), 0), MFINE - 1);
        int m3 = min(max((int)(v.w * (float)MFINE), 0), MFINE - 1);
        atomicAdd(&h[m0], 1u);
        atomicAdd(&h[m1], 1u);
        atomicAdd(&h[m2], 1u);
        atomicAdd(&h[m3], 1u);
    }
    __syncthreads();

    for (int i = t; i < MFINE; i += 256) {
        unsigned int c = h[i];
        if (c) atomicAdd(&fine[s * MFINE + i], c);
    }
}

// ---------------------------------------------------------------------------
// K2: soft histogram = convolution of fine counts with the sigmoid-difference
// membership f(d) = sig(5(d+0.5)) - sig(5(d-0.5)).  128 blocks = (slice, bin).
// ---------------------------------------------------------------------------
__global__ __launch_bounds__(256) void soft_kernel(const unsigned int* __restrict__ fine,
                                                   float* __restrict__ soft) {
    const int blk = blockIdx.x;
    const int s = blk >> 5;
    const int c = blk & 31;
    const int t = threadIdx.x;

    float acc = 0.f;
    for (int i = t; i < MFINE; i += 256) {
        unsigned int cnt = fine[s * MFINE + i];
        if (cnt) {
            // bin center in y = img*31 units
            float d  = (i + 0.5f) * (31.0f / (float)MFINE) - (float)c;
            float fa = 1.f / (1.f + __expf(-5.f * (d + 0.5f)));
            float fb = 1.f / (1.f + __expf(-5.f * (d - 0.5f)));
            acc += (float)cnt * (fa - fb);
        }
    }
    // wave + block reduction
    #pragma unroll
    for (int o = 32; o > 0; o >>= 1) acc += __shfl_down(acc, o, 64);
    __shared__ float wsum[4];
    if ((t & 63) == 0) wsum[t >> 6] = acc;
    __syncthreads();
    if (t == 0) soft[s * BINS + c] = wsum[0] + wsum[1] + wsum[2] + wsum[3];
}

// ---------------------------------------------------------------------------
// K3: normalize + cumsum + argmin matching table; emit g_k and g_k*table_k.
// 1 block x 64 threads.
// ---------------------------------------------------------------------------
__global__ __launch_bounds__(64) void table_kernel(const float* __restrict__ soft,
                                                   float* __restrict__ gt,
                                                   float* __restrict__ gd) {
    __shared__ float cdf[NSLC][BINS];
    const int t = threadIdx.x;

    if (t < NSLC) {
        float sum = 0.f;
        for (int c = 0; c < BINS; ++c) sum += soft[t * BINS + c];
        float inv = 1.f / fmaxf(sum, 1e-12f);
        float run = 0.f;
        for (int c = 0; c < BINS; ++c) {
            run += soft[t * BINS + c];
            cdf[t][c] = run * inv;
        }
    }
    __syncthreads();

    const int s = t >> 5;   // dst slice 0..1
    const int i = t & 31;   // dst bin
    float v = cdf[s][i];
    int best = 0;
    float bd = fabsf(v - cdf[s + 2][0]);
    #pragma unroll
    for (int j = 1; j < BINS; ++j) {
        float dj = fabsf(v - cdf[s + 2][j]);
        if (dj < bd) { bd = dj; best = j; }   // strict < keeps lowest index on ties
    }
    float g = __expf(-(float)(i * i) * (1.0f / 50.0f));
    gt[s * BINS + i] = g * (float)best;
    if (s == 0) gd[i] = g;
}

// ---------------------------------------------------------------------------
// K4: apply. softmax(-(y-k)^2/50) factorized: w_k ∝ r^k * g_k, r = e^{y/25}.
// 512 blocks (256/slice) x 256 threads; 16 voxels/thread, k-loop outside the
// voxel working set so the 32 float2 LDS reads are amortized over 16 voxels.
// ---------------------------------------------------------------------------
__global__ __launch_bounds__(256) void apply_kernel(const float4* __restrict__ dst4,
                                                    const float* __restrict__ gt,
                                                    const float* __restrict__ gd,
                                                    float4* __restrict__ out4) {
    __shared__ float2 sgg[BINS];   // (gd_k, gt_k) for this slice
    const int t  = threadIdx.x;
    const int b  = blockIdx.x;
    const int s  = b >> 8;
    const int ib = b & 255;

    if (t < BINS) sgg[t] = make_float2(gd[t], gt[s * BINS + t]);
    __syncthreads();

    const int base = s * (NVOX / 4) + ib * 1024;

    float4 v[4];
    #pragma unroll
    for (int j = 0; j < 4; ++j) v[j] = dst4[base + j * 256 + t];
    float* x = (float*)v;   // 16 voxel values, fully unrolled below

    float r[16], u[16], num[16], den[16];
    #pragma unroll
    for (int i = 0; i < 16; ++i) {
        float y = x[i] * 31.0f;
        r[i] = __expf(y * (1.0f / 25.0f));
        u[i] = 1.0f;
        num[i] = 0.0f;
        den[i] = 0.0f;
    }

    #pragma unroll
    for (int k = 0; k < BINS; ++k) {
        float2 gg = sgg[k];   // one ds_read_b64, broadcast across the wave
        #pragma unroll
        for (int i = 0; i < 16; ++i) {
            num[i] = fmaf(u[i], gg.y, num[i]);
            den[i] = fmaf(u[i], gg.x, den[i]);
            u[i] *= r[i];
        }
    }

    #pragma unroll
    for (int i = 0; i < 16; ++i) {
        x[i] = num[i] * __builtin_amdgcn_rcpf(den[i]) * (1.0f / 31.0f);
    }
    #pragma unroll
    for (int j = 0; j < 4; ++j) out4[base + j * 256 + t] = v[j];
}

// ---------------------------------------------------------------------------
extern "C" void kernel_launch(void* const* d_in, const int* in_sizes, int n_in,
                              void* d_out, int out_size, void* d_ws, size_t ws_size,
                              hipStream_t stream) {
    const float4* dst4 = (const float4*)d_in[0];
    const float4* ref4 = (const float4*)d_in[1];
    float4* out4 = (float4*)d_out;

    unsigned int* fine = (unsigned int*)d_ws;
    float* soft = (float*)((char*)d_ws + 32768);
    float* gt   = (float*)((char*)d_ws + 33280);
    float* gd   = (float*)((char*)d_ws + 33536);

    // zero the fine histograms (d_ws is poisoned 0xAA before every call)
    hipMemsetAsync(fine, 0, NSLC * MFINE * sizeof(unsigned int), stream);

    hipLaunchKernelGGL(hist_kernel,  dim3(256), dim3(256), 0, stream, dst4, ref4, fine);
    hipLaunchKernelGGL(soft_kernel,  dim3(128), dim3(256), 0, stream, fine, soft);
    hipLaunchKernelGGL(table_kernel, dim3(1),   dim3(64),  0, stream, soft, gt, gd);
    hipLaunchKernelGGL(apply_kernel, dim3(512), dim3(256), 0, stream, dst4, gt, gd, out4);
}